// Round 1
// baseline (277.648 us; speedup 1.0000x reference)
//
#include <hip/hip_runtime.h>
#include <math.h>

#define D   128
#define DP  64
#define H   8
#define DH  16
#define DO  32
#define NB  2
#define L   320
#define NR  (NB * L)   // 640 rows

// ---------------------------------------------------------------------------
// K1: LayerNorm1 + fused QKV projection. 4 rows per block, 128 threads.
// ---------------------------------------------------------------------------
__global__ __launch_bounds__(128) void k1_ln_qkv(
    const float* __restrict__ x, const float* __restrict__ Wq,
    const float* __restrict__ Wk, const float* __restrict__ Wv,
    const float* __restrict__ g, const float* __restrict__ bb,
    float* __restrict__ qkv) {
  __shared__ float xs[4][D];
  __shared__ float stat[4][2]; // mu, rsqrt
  const int t = threadIdx.x;
  const int r0 = blockIdx.x * 4;
#pragma unroll
  for (int r = 0; r < 4; ++r) xs[r][t] = x[(r0 + r) * D + t];
  __syncthreads();
  const int w = t >> 6, lane = t & 63;
#pragma unroll
  for (int rr = 0; rr < 2; ++rr) {
    int r = w * 2 + rr;
    float a = xs[r][lane], c = xs[r][lane + 64];
    float s = a + c, s2 = a * a + c * c;
#pragma unroll
    for (int off = 32; off >= 1; off >>= 1) {
      s += __shfl_xor(s, off, 64);
      s2 += __shfl_xor(s2, off, 64);
    }
    if (lane == 0) {
      float mu = s * (1.0f / D);
      float var = s2 * (1.0f / D) - mu * mu;
      stat[r][0] = mu;
      stat[r][1] = rsqrtf(var + 1e-5f);
    }
  }
  __syncthreads();
  const float gv = g[t], bv = bb[t];
#pragma unroll
  for (int r = 0; r < 4; ++r)
    xs[r][t] = (xs[r][t] - stat[r][0]) * stat[r][1] * gv + bv;
  __syncthreads();
  float aq[4] = {0, 0, 0, 0}, ak[4] = {0, 0, 0, 0}, av[4] = {0, 0, 0, 0};
#pragma unroll 4
  for (int k = 0; k < D; ++k) {
    float wq = Wq[k * D + t], wk = Wk[k * D + t], wv = Wv[k * D + t];
#pragma unroll
    for (int r = 0; r < 4; ++r) {
      float xv = xs[r][k];
      aq[r] += xv * wq;
      ak[r] += xv * wk;
      av[r] += xv * wv;
    }
  }
#pragma unroll
  for (int r = 0; r < 4; ++r) {
    int base = (r0 + r) * 384 + t;
    qkv[base] = aq[r];
    qkv[base + 128] = ak[r];
    qkv[base + 256] = av[r];
  }
}

// ---------------------------------------------------------------------------
// K2: bias[b,h,i,j] = sum_p z[b,i,j,p] * Wb[p,h].  Tile of 64 j's per block.
// ---------------------------------------------------------------------------
__global__ __launch_bounds__(256) void k2_bias(
    const float* __restrict__ z, const float* __restrict__ Wb,
    float* __restrict__ bias) {
  __shared__ float zs[64][65];          // padded: banks (j+p)%32, 2-way = free
  __shared__ float wbs[DP * H];
  const int t = threadIdx.x;
  const int jt = blockIdx.x, i = blockIdx.y, b = blockIdx.z;
  const float* zsrc = z + (((size_t)(b * L + i) * L) + jt * 64) * DP;
#pragma unroll
  for (int q = 0; q < 16; ++q) {
    int idx = q * 256 + t;
    zs[idx >> 6][idx & 63] = zsrc[idx];
  }
  for (int q = t; q < DP * H; q += 256) wbs[q] = Wb[q];
  __syncthreads();
  const int h0 = t >> 6, j = t & 63;
  float a0 = 0, a1 = 0;
#pragma unroll 8
  for (int p = 0; p < 64; ++p) {
    float zv = zs[j][p];
    a0 += zv * wbs[p * H + h0];
    a1 += zv * wbs[p * H + h0 + 4];
  }
  size_t o0 = (((size_t)(b * H + h0) * L) + i) * L + jt * 64 + j;
  bias[o0] = a0;
  bias[o0 + (size_t)4 * L * L] = a1;
}

// ---------------------------------------------------------------------------
// K3: attention per (b,h, i-tile of 16).  K/V staged in LDS (stride 17).
// ---------------------------------------------------------------------------
__global__ __launch_bounds__(256) void k3_attn(
    const float* __restrict__ qkv, const float* __restrict__ bias,
    float* __restrict__ ao) {
  __shared__ float Ks[L * 17];
  __shared__ float Vs[L * 17];
  __shared__ float qs[16 * DH];
  __shared__ float ps[4][L];
  const int t = threadIdx.x;
  const int i0 = blockIdx.x * 16, h = blockIdx.y, b = blockIdx.z;
  for (int idx = t; idx < L * DH; idx += 256) {
    int j = idx >> 4, d = idx & 15;
    const float* src = qkv + (size_t)(b * L + j) * 384 + h * DH + d;
    Ks[j * 17 + d] = src[128];
    Vs[j * 17 + d] = src[256];
  }
  {
    int ii = t >> 4, d = t & 15;
    qs[t] = qkv[(size_t)(b * L + i0 + ii) * 384 + h * DH + d] * 0.25f; // 1/sqrt(16)
  }
  __syncthreads();
  const int w = t >> 6, lane = t & 63;
  for (int ii = w; ii < 16; ii += 4) {
    const int i = i0 + ii;
    const float* brow = bias + (((size_t)(b * H + h) * L) + i) * L;
    float sc[5], m = -1e30f;
#pragma unroll
    for (int it = 0; it < 5; ++it) {
      int j = it * 64 + lane;
      float s = 0;
#pragma unroll
      for (int d = 0; d < DH; ++d) s += qs[ii * DH + d] * Ks[j * 17 + d];
      s += brow[j];
      sc[it] = s;
      m = fmaxf(m, s);
    }
#pragma unroll
    for (int off = 32; off >= 1; off >>= 1) m = fmaxf(m, __shfl_xor(m, off, 64));
    float sum = 0;
#pragma unroll
    for (int it = 0; it < 5; ++it) {
      sc[it] = __expf(sc[it] - m);
      sum += sc[it];
    }
#pragma unroll
    for (int off = 32; off >= 1; off >>= 1) sum += __shfl_xor(sum, off, 64);
    float inv = 1.0f / sum;
#pragma unroll
    for (int it = 0; it < 5; ++it) ps[w][it * 64 + lane] = sc[it];
    // wave-internal LDS RAW: in-order DS ops within a wave, no barrier needed
    int d = lane & 15, grp = lane >> 4;
    float acc = 0;
#pragma unroll 4
    for (int j = grp * 80; j < grp * 80 + 80; ++j) acc += ps[w][j] * Vs[j * 17 + d];
    acc += __shfl_xor(acc, 16, 64);
    acc += __shfl_xor(acc, 32, 64);
    if (lane < 16) ao[(size_t)(b * L + i) * D + h * DH + d] = acc * inv;
  }
}

// ---------------------------------------------------------------------------
// K4: fused per-row pass: Wo-proj + residual -> LN2 -> FFN(gelu) + residual
//     -> write x out -> p1/p2 projections.  One row per block, 256 threads.
// ---------------------------------------------------------------------------
__global__ __launch_bounds__(256) void k4_rowpass(
    const float* __restrict__ x, const float* __restrict__ ao,
    const float* __restrict__ Wo, const float* __restrict__ bo,
    const float* __restrict__ g2, const float* __restrict__ b2,
    const float* __restrict__ W1, const float* __restrict__ bf1,
    const float* __restrict__ W2, const float* __restrict__ bf2,
    const float* __restrict__ Wp1, const float* __restrict__ bp1,
    const float* __restrict__ Wp2, const float* __restrict__ bp2,
    float* __restrict__ out_x, float* __restrict__ p1, float* __restrict__ p2) {
  __shared__ float buf[D];   // ao row, then xn2 row
  __shared__ float x1s[D];
  __shared__ float hs[4 * D];
  __shared__ float red[2][D];
  __shared__ float stat[2];
  const int t = threadIdx.x;
  const int row = blockIdx.x;
  const int c = t & 127, half = t >> 7;
  if (t < D) buf[t] = ao[row * D + t];
  __syncthreads();
  float acc = 0;
#pragma unroll 4
  for (int k = half * 64; k < half * 64 + 64; ++k) acc += buf[k] * Wo[k * D + c];
  red[half][c] = acc;
  __syncthreads();
  if (t < D) x1s[t] = x[row * D + t] + red[0][t] + red[1][t] + bo[t];
  __syncthreads();
  if (t < 64) {
    float a = x1s[t], bv = x1s[t + 64];
    float s = a + bv, s2 = a * a + bv * bv;
#pragma unroll
    for (int off = 32; off >= 1; off >>= 1) {
      s += __shfl_xor(s, off, 64);
      s2 += __shfl_xor(s2, off, 64);
    }
    if (t == 0) {
      float mu = s * (1.0f / D);
      stat[0] = mu;
      stat[1] = rsqrtf(s2 * (1.0f / D) - mu * mu + 1e-5f);
    }
  }
  __syncthreads();
  if (t < D) buf[t] = (x1s[t] - stat[0]) * stat[1] * g2[t] + b2[t];
  __syncthreads();
  float a1 = 0, a2 = 0;
#pragma unroll 4
  for (int k = 0; k < D; ++k) {
    float xv = buf[k];
    a1 += xv * W1[k * 512 + t];
    a2 += xv * W1[k * 512 + t + 256];
  }
  a1 += bf1[t];
  a2 += bf1[t + 256];
  hs[t] = 0.5f * a1 * (1.0f + erff(a1 * 0.70710678118654752f));
  hs[t + 256] = 0.5f * a2 * (1.0f + erff(a2 * 0.70710678118654752f));
  __syncthreads();
  acc = 0;
#pragma unroll 4
  for (int k = half * 256; k < half * 256 + 256; ++k) acc += hs[k] * W2[k * D + c];
  red[half][c] = acc;
  __syncthreads();
  if (t < D) {
    float x2 = x1s[t] + red[0][t] + red[1][t] + bf2[t];
    x1s[t] = x2;  // reuse as x2 row
    out_x[row * D + t] = x2;
  }
  __syncthreads();
  if (t < 64) {
    const float* W = (t < 32) ? Wp1 : Wp2;
    const float* bp = (t < 32) ? bp1 : bp2;
    int cc = t & 31;
    float a = 0;
#pragma unroll 4
    for (int k = 0; k < D; ++k) a += x1s[k] * W[k * DO + cc];
    a += bp[cc];
    if (t < 32) p1[row * DO + cc] = a;
    else        p2[row * DO + cc] = a;
  }
}

// ---------------------------------------------------------------------------
// K5: T[row,d,p] = sum_c p1[row,c] * Wz[c*32+d, p].  4 rows per block.
// ---------------------------------------------------------------------------
__global__ __launch_bounds__(256) void k5_T(
    const float* __restrict__ p1, const float* __restrict__ Wz,
    float* __restrict__ T) {
  __shared__ float p1s[4 * DO];
  const int t = threadIdx.x;
  const int r0 = blockIdx.x * 4;
  if (t < 128) p1s[t] = p1[r0 * DO + t];
  __syncthreads();
  float acc[4][8];
#pragma unroll
  for (int r = 0; r < 4; ++r)
#pragma unroll
    for (int q = 0; q < 8; ++q) acc[r][q] = 0.0f;
  for (int cc = 0; cc < 32; ++cc) {
    float wv[8];
#pragma unroll
    for (int q = 0; q < 8; ++q) wv[q] = Wz[(size_t)cc * 2048 + q * 256 + t];
#pragma unroll
    for (int r = 0; r < 4; ++r) {
      float pv = p1s[r * DO + cc];
#pragma unroll
      for (int q = 0; q < 8; ++q) acc[r][q] += pv * wv[q];
    }
  }
#pragma unroll
  for (int r = 0; r < 4; ++r)
#pragma unroll
    for (int q = 0; q < 8; ++q)
      T[(size_t)(r0 + r) * 2048 + q * 256 + t] = acc[r][q];
}

// ---------------------------------------------------------------------------
// K6: z_out = LN(z + sum_d p2[j,d]*T[i,d,:] + bz).  Block per (b,i); lane = p.
// T column lives in 32 registers per lane; LN = wave64 shuffle reduce.
// ---------------------------------------------------------------------------
__global__ __launch_bounds__(256) void k6_zout(
    const float* __restrict__ z, const float* __restrict__ T,
    const float* __restrict__ p2, const float* __restrict__ bz,
    const float* __restrict__ gp, const float* __restrict__ bp,
    float* __restrict__ zout) {
  __shared__ float p2s[L * DO];  // 40 KB
  const int t = threadIdx.x;
  const int i = blockIdx.x, b = blockIdx.y;
  for (int idx = t; idx < L * DO; idx += 256) p2s[idx] = p2[b * L * DO + idx];
  const int w = t >> 6, lane = t & 63;
  const size_t row = (size_t)(b * L + i);
  float treg[32];
#pragma unroll
  for (int d = 0; d < 32; ++d) treg[d] = T[row * 2048 + d * 64 + lane];
  const float bzv = bz[lane], gv = gp[lane], bv = bp[lane];
  __syncthreads();
  const float* zrow = z + row * L * DP;
  float* orow = zout + row * L * DP;
  for (int j = w; j < L; j += 4) {
    const float4* pj = (const float4*)&p2s[j * DO];
    float upd = bzv;
#pragma unroll
    for (int dd = 0; dd < 8; ++dd) {
      float4 pv = pj[dd];
      upd += pv.x * treg[dd * 4] + pv.y * treg[dd * 4 + 1] +
             pv.z * treg[dd * 4 + 2] + pv.w * treg[dd * 4 + 3];
    }
    float y = zrow[j * DP + lane] + upd;
    float s = y, s2 = y * y;
#pragma unroll
    for (int off = 32; off >= 1; off >>= 1) {
      s += __shfl_xor(s, off, 64);
      s2 += __shfl_xor(s2, off, 64);
    }
    float mu = s * (1.0f / DP);
    float var = s2 * (1.0f / DP) - mu * mu;
    y = (y - mu) * rsqrtf(var + 1e-5f) * gv + bv;
    orow[j * DP + lane] = y;
  }
}

// ---------------------------------------------------------------------------
extern "C" void kernel_launch(void* const* d_in, const int* in_sizes, int n_in,
                              void* d_out, int out_size, void* d_ws, size_t ws_size,
                              hipStream_t stream) {
  const float* x      = (const float*)d_in[0];
  const float* z      = (const float*)d_in[1];
  const float* Wq     = (const float*)d_in[2];
  const float* Wk     = (const float*)d_in[3];
  const float* Wv     = (const float*)d_in[4];
  const float* Wb     = (const float*)d_in[5];
  const float* Wo     = (const float*)d_in[6];
  const float* bo     = (const float*)d_in[7];
  const float* ln1_g  = (const float*)d_in[8];
  const float* ln1_b  = (const float*)d_in[9];
  const float* W_ffn1 = (const float*)d_in[10];
  const float* b_ffn1 = (const float*)d_in[11];
  const float* W_ffn2 = (const float*)d_in[12];
  const float* b_ffn2 = (const float*)d_in[13];
  const float* ln2_g  = (const float*)d_in[14];
  const float* ln2_b  = (const float*)d_in[15];
  const float* Wp1    = (const float*)d_in[16];
  const float* bp1    = (const float*)d_in[17];
  const float* Wp2    = (const float*)d_in[18];
  const float* bp2    = (const float*)d_in[19];
  const float* Wz     = (const float*)d_in[20];
  const float* bz     = (const float*)d_in[21];
  const float* lnp_g  = (const float*)d_in[22];
  const float* lnp_b  = (const float*)d_in[23];

  float* ws   = (float*)d_ws;
  float* qkv  = ws;                   // 640*384    = 245760
  float* bias = qkv + 245760;         // 2*8*320*320= 1638400
  float* ao   = bias + 1638400;       // 640*128    = 81920
  float* p1   = ao + 81920;           // 640*32     = 20480
  float* p2   = p1 + 20480;           // 640*32     = 20480
  float* T    = p2 + 20480;           // 640*2048   = 1310720  (total ~13.3 MB)

  float* out_x = (float*)d_out;           // 81920
  float* out_z = out_x + 81920;           // 13107200

  hipLaunchKernelGGL(k1_ln_qkv, dim3(NR / 4), dim3(128), 0, stream,
                     x, Wq, Wk, Wv, ln1_g, ln1_b, qkv);
  hipLaunchKernelGGL(k2_bias, dim3(L / 64, L, NB), dim3(256), 0, stream,
                     z, Wb, bias);
  hipLaunchKernelGGL(k3_attn, dim3(L / 16, H, NB), dim3(256), 0, stream,
                     qkv, bias, ao);
  hipLaunchKernelGGL(k4_rowpass, dim3(NR), dim3(256), 0, stream,
                     x, ao, Wo, bo, ln2_g, ln2_b, W_ffn1, b_ffn1,
                     W_ffn2, b_ffn2, Wp1, bp1, Wp2, bp2, out_x, p1, p2);
  hipLaunchKernelGGL(k5_T, dim3(NR / 4), dim3(256), 0, stream, p1, Wz, T);
  hipLaunchKernelGGL(k6_zout, dim3(L, NB), dim3(256), 0, stream,
                     z, T, p2, bz, lnp_g, lnp_b, out_z);
}

// Round 2
// 244.869 us; speedup vs baseline: 1.1339x; 1.1339x over previous
//
#include <hip/hip_runtime.h>
#include <math.h>

#define D   128
#define DP  64
#define H   8
#define DH  16
#define DO  32
#define NB  2
#define L   320
#define NR  (NB * L)   // 640 rows

// ---------------------------------------------------------------------------
// K1: LayerNorm1 + fused QKV projection. 2 rows per block, 256 threads.
// ---------------------------------------------------------------------------
__global__ __launch_bounds__(256) void k1_ln_qkv(
    const float* __restrict__ x, const float* __restrict__ Wq,
    const float* __restrict__ Wk, const float* __restrict__ Wv,
    const float* __restrict__ g, const float* __restrict__ bb,
    float* __restrict__ qkv) {
  __shared__ float xs[2][D];
  __shared__ float stat[2][2];
  const int t = threadIdx.x;
  const int r0 = blockIdx.x * 2;
  const int row = t >> 7, c = t & 127;
  xs[row][c] = x[(r0 + row) * D + c];
  __syncthreads();
  const int w = t >> 6, lane = t & 63;
  if (w < 2) {  // wave w computes LN stats for row w
    float a = xs[w][lane], cc = xs[w][lane + 64];
    float s = a + cc, s2 = a * a + cc * cc;
#pragma unroll
    for (int off = 32; off >= 1; off >>= 1) {
      s += __shfl_xor(s, off, 64);
      s2 += __shfl_xor(s2, off, 64);
    }
    if (lane == 0) {
      float mu = s * (1.0f / D);
      float var = s2 * (1.0f / D) - mu * mu;
      stat[w][0] = mu;
      stat[w][1] = rsqrtf(var + 1e-5f);
    }
  }
  __syncthreads();
  float xn = (xs[row][c] - stat[row][0]) * stat[row][1] * g[c] + bb[c];
  xs[row][c] = xn;   // own-element RMW, no race
  __syncthreads();
  float aq = 0, ak = 0, av = 0;
#pragma unroll 4
  for (int k = 0; k < D; ++k) {
    float wq = Wq[k * D + c], wk = Wk[k * D + c], wv = Wv[k * D + c];
    float xv = xs[row][k];
    aq += xv * wq;
    ak += xv * wk;
    av += xv * wv;
  }
  int base = (r0 + row) * 384 + c;
  qkv[base] = aq;
  qkv[base + 128] = ak;
  qkv[base + 256] = av;
}

// ---------------------------------------------------------------------------
// K2: bias[b,h,i,j] = sum_p z[b,i,j,p] * Wb[p,h].  Tile of 64 j's per block.
// ---------------------------------------------------------------------------
__global__ __launch_bounds__(256) void k2_bias(
    const float* __restrict__ z, const float* __restrict__ Wb,
    float* __restrict__ bias) {
  __shared__ float zs[64][65];          // padded: banks (j+p)%32, 2-way = free
  __shared__ float wbs[DP * H];
  const int t = threadIdx.x;
  const int jt = blockIdx.x, i = blockIdx.y, b = blockIdx.z;
  const float4* zsrc4 =
      (const float4*)(z + (((size_t)(b * L + i) * L) + jt * 64) * DP);
#pragma unroll
  for (int q = 0; q < 4; ++q) {
    int idx4 = q * 256 + t;             // 1024 float4s = 64 rows x 16
    float4 v = zsrc4[idx4];
    int r = idx4 >> 4, c0 = (idx4 & 15) * 4;
    zs[r][c0] = v.x; zs[r][c0 + 1] = v.y; zs[r][c0 + 2] = v.z; zs[r][c0 + 3] = v.w;
  }
  for (int q = t; q < DP * H; q += 256) wbs[q] = Wb[q];
  __syncthreads();
  const int h0 = t >> 6, j = t & 63;
  float a0 = 0, a1 = 0;
#pragma unroll 8
  for (int p = 0; p < 64; ++p) {
    float zv = zs[j][p];
    a0 += zv * wbs[p * H + h0];
    a1 += zv * wbs[p * H + h0 + 4];
  }
  size_t o0 = (((size_t)(b * H + h0) * L) + i) * L + jt * 64 + j;
  bias[o0] = a0;
  bias[o0 + (size_t)4 * L * L] = a1;
}

// ---------------------------------------------------------------------------
// K3: attention per (b,h, i-tile of 8).  512 threads, one row per wave.
// ---------------------------------------------------------------------------
__global__ __launch_bounds__(512) void k3_attn(
    const float* __restrict__ qkv, const float* __restrict__ bias,
    float* __restrict__ ao) {
  __shared__ float Ks[L * 17];
  __shared__ float Vs[L * 17];
  __shared__ float qs[8 * DH];
  __shared__ float ps[8][L];
  const int t = threadIdx.x;
  const int i0 = blockIdx.x * 8, h = blockIdx.y, b = blockIdx.z;
  for (int idx = t; idx < L * DH; idx += 512) {
    int j = idx >> 4, d = idx & 15;
    const float* src = qkv + (size_t)(b * L + j) * 384 + h * DH + d;
    Ks[j * 17 + d] = src[128];
    Vs[j * 17 + d] = src[256];
  }
  if (t < 128) {
    int ii = t >> 4, d = t & 15;
    qs[t] = qkv[(size_t)(b * L + i0 + ii) * 384 + h * DH + d] * 0.25f; // 1/sqrt(16)
  }
  __syncthreads();
  const int w = t >> 6, lane = t & 63;
  const int i = i0 + w;   // one row per wave
  const float* brow = bias + (((size_t)(b * H + h) * L) + i) * L;
  float sc[5], m = -1e30f;
#pragma unroll
  for (int it = 0; it < 5; ++it) {
    int j = it * 64 + lane;
    float s = 0;
#pragma unroll
    for (int d = 0; d < DH; ++d) s += qs[w * DH + d] * Ks[j * 17 + d];
    s += brow[j];
    sc[it] = s;
    m = fmaxf(m, s);
  }
#pragma unroll
  for (int off = 32; off >= 1; off >>= 1) m = fmaxf(m, __shfl_xor(m, off, 64));
  float sum = 0;
#pragma unroll
  for (int it = 0; it < 5; ++it) {
    sc[it] = __expf(sc[it] - m);
    sum += sc[it];
  }
#pragma unroll
  for (int off = 32; off >= 1; off >>= 1) sum += __shfl_xor(sum, off, 64);
  float inv = 1.0f / sum;
#pragma unroll
  for (int it = 0; it < 5; ++it) ps[w][it * 64 + lane] = sc[it];
  // wave-internal LDS RAW: DS ops are in-order within a wave, no barrier needed
  int d = lane & 15, grp = lane >> 4;
  float acc = 0;
#pragma unroll 4
  for (int j = grp * 80; j < grp * 80 + 80; ++j) acc += ps[w][j] * Vs[j * 17 + d];
  acc += __shfl_xor(acc, 16, 64);
  acc += __shfl_xor(acc, 32, 64);
  if (lane < 16) ao[(size_t)(b * L + i) * D + h * DH + d] = acc * inv;
}

// ---------------------------------------------------------------------------
// K45: fused per-row pass: Wo-proj + residual -> LN2 -> FFN(gelu) + residual
//      -> x out -> p1/p2 projections -> T[row,d,p] = sum_c p1[c]*Wz4[c,d,p].
//      One row per block, 512 threads; every GEMM splits k across quarters.
// ---------------------------------------------------------------------------
__global__ __launch_bounds__(512) void k45_rowpass(
    const float* __restrict__ x, const float* __restrict__ ao,
    const float* __restrict__ Wo, const float* __restrict__ bo,
    const float* __restrict__ g2, const float* __restrict__ b2,
    const float* __restrict__ W1, const float* __restrict__ bf1,
    const float* __restrict__ W2, const float* __restrict__ bf2,
    const float* __restrict__ Wp1, const float* __restrict__ bp1,
    const float* __restrict__ Wp2, const float* __restrict__ bp2,
    const float* __restrict__ Wz,
    float* __restrict__ out_x, float* __restrict__ p1, float* __restrict__ p2,
    float* __restrict__ T) {
  __shared__ float buf[D];      // ao row, then xn2 row
  __shared__ float x1s[D];
  __shared__ float x2s[D];
  __shared__ float hs[4 * D];
  __shared__ float red[4][D];
  __shared__ float redp[4][64];
  __shared__ float ps_row[64];
  __shared__ float stat[2];
  const int t = threadIdx.x;
  const int row = blockIdx.x;
  const int c = t & 127, q = t >> 7;
  if (t < D) buf[t] = ao[row * D + t];
  __syncthreads();
  {  // Wo projection: k split in 4 chunks of 32
    float a = 0;
#pragma unroll
    for (int k = q * 32; k < q * 32 + 32; ++k) a += buf[k] * Wo[k * D + c];
    red[q][c] = a;
  }
  __syncthreads();
  if (t < D)
    x1s[t] = x[row * D + t] + red[0][t] + red[1][t] + red[2][t] + red[3][t] + bo[t];
  __syncthreads();
  if (t < 64) {
    float a = x1s[t], bv = x1s[t + 64];
    float s = a + bv, s2 = a * a + bv * bv;
#pragma unroll
    for (int off = 32; off >= 1; off >>= 1) {
      s += __shfl_xor(s, off, 64);
      s2 += __shfl_xor(s2, off, 64);
    }
    if (t == 0) {
      float mu = s * (1.0f / D);
      stat[0] = mu;
      stat[1] = rsqrtf(s2 * (1.0f / D) - mu * mu + 1e-5f);
    }
  }
  __syncthreads();
  if (t < D) buf[t] = (x1s[t] - stat[0]) * stat[1] * g2[t] + b2[t];
  __syncthreads();
  {  // FFN1 + gelu: one output per thread
    float a = bf1[t];
#pragma unroll 4
    for (int k = 0; k < D; ++k) a += buf[k] * W1[k * 512 + t];
    hs[t] = 0.5f * a * (1.0f + erff(a * 0.70710678118654752f));
  }
  __syncthreads();
  {  // FFN2: k split in 4 chunks of 128
    float a = 0;
#pragma unroll 4
    for (int k = q * 128; k < q * 128 + 128; ++k) a += hs[k] * W2[k * D + c];
    red[q][c] = a;
  }
  __syncthreads();
  if (t < D) {
    float x2 = x1s[t] + red[0][t] + red[1][t] + red[2][t] + red[3][t] + bf2[t];
    x2s[t] = x2;
    out_x[row * D + t] = x2;
  }
  __syncthreads();
  if (t < 256) {  // p1/p2 projections: 64 outputs x 4 k-chunks
    int o = t & 63, q2 = t >> 6;
    const float* W = (o < 32) ? Wp1 : Wp2;
    int cc = o & 31;
    float a = 0;
#pragma unroll
    for (int k = q2 * 32; k < q2 * 32 + 32; ++k) a += x2s[k] * W[k * DO + cc];
    redp[q2][o] = a;
  }
  __syncthreads();
  if (t < 64) {
    float a = redp[0][t] + redp[1][t] + redp[2][t] + redp[3][t] +
              ((t < 32) ? bp1[t] : bp2[t & 31]);
    ps_row[t] = a;
    if (t < 32) p1[row * DO + t] = a;
    else        p2[row * DO + (t & 31)] = a;
  }
  __syncthreads();
  {  // T[row, d, p] = sum_c p1[c] * Wz[c*2048 + d*64 + p]
#pragma unroll
    for (int qq = 0; qq < 4; ++qq) {
      int idx = qq * 512 + t;
      float a = 0;
#pragma unroll 8
      for (int cc = 0; cc < 32; ++cc) a += ps_row[cc] * Wz[(size_t)cc * 2048 + idx];
      T[(size_t)row * 2048 + idx] = a;
    }
  }
}

// ---------------------------------------------------------------------------
// K6: z_out = LN(z + sum_d p2[j,d]*T[i,d,:] + bz).  Block per (b,i,j-tile of 80).
// T column in 32 registers per lane (lane=p); LN = wave64 shuffle reduce.
// ---------------------------------------------------------------------------
__global__ __launch_bounds__(256) void k6_zout(
    const float* __restrict__ z, const float* __restrict__ T,
    const float* __restrict__ p2, const float* __restrict__ bz,
    const float* __restrict__ gp, const float* __restrict__ bp,
    float* __restrict__ zout) {
  __shared__ float p2s[80 * DO];  // 10 KB
  const int t = threadIdx.x;
  const int jt = blockIdx.x;      // 0..3: tile of 80 j's
  const int i = blockIdx.y, b = blockIdx.z;
  const size_t row = (size_t)(b * L + i);
  const float* psrc = p2 + ((size_t)b * L + jt * 80) * DO;
#pragma unroll
  for (int qq = 0; qq < 10; ++qq) p2s[qq * 256 + t] = psrc[qq * 256 + t];
  const int w = t >> 6, lane = t & 63;
  float treg[32];
#pragma unroll
  for (int d = 0; d < 32; ++d) treg[d] = T[row * 2048 + d * 64 + lane];
  const float bzv = bz[lane], gv = gp[lane], bv = bp[lane];
  __syncthreads();
  const float* zrow = z + (row * L + (size_t)jt * 80) * DP;
  float* orow = zout + (row * L + (size_t)jt * 80) * DP;
  for (int j0 = 0; j0 < 20; j0 += 2) {   // 2-way unroll for ILP
    const int jl0 = w * 20 + j0, jl1 = jl0 + 1;
    const float4* pj0 = (const float4*)&p2s[jl0 * 32];
    const float4* pj1 = (const float4*)&p2s[jl1 * 32];
    float u0 = bzv, u1 = bzv;
#pragma unroll
    for (int dd = 0; dd < 8; ++dd) {
      float4 a = pj0[dd], bq = pj1[dd];
      u0 += a.x * treg[dd * 4] + a.y * treg[dd * 4 + 1] +
            a.z * treg[dd * 4 + 2] + a.w * treg[dd * 4 + 3];
      u1 += bq.x * treg[dd * 4] + bq.y * treg[dd * 4 + 1] +
            bq.z * treg[dd * 4 + 2] + bq.w * treg[dd * 4 + 3];
    }
    float y0 = zrow[jl0 * DP + lane] + u0;
    float y1 = zrow[jl1 * DP + lane] + u1;
    float s0 = y0, q0 = y0 * y0, s1 = y1, q1 = y1 * y1;
#pragma unroll
    for (int off = 32; off >= 1; off >>= 1) {
      s0 += __shfl_xor(s0, off, 64);
      q0 += __shfl_xor(q0, off, 64);
      s1 += __shfl_xor(s1, off, 64);
      q1 += __shfl_xor(q1, off, 64);
    }
    float mu0 = s0 * (1.0f / DP), var0 = q0 * (1.0f / DP) - mu0 * mu0;
    float mu1 = s1 * (1.0f / DP), var1 = q1 * (1.0f / DP) - mu1 * mu1;
    orow[jl0 * DP + lane] = (y0 - mu0) * rsqrtf(var0 + 1e-5f) * gv + bv;
    orow[jl1 * DP + lane] = (y1 - mu1) * rsqrtf(var1 + 1e-5f) * gv + bv;
  }
}

// ---------------------------------------------------------------------------
extern "C" void kernel_launch(void* const* d_in, const int* in_sizes, int n_in,
                              void* d_out, int out_size, void* d_ws, size_t ws_size,
                              hipStream_t stream) {
  const float* x      = (const float*)d_in[0];
  const float* z      = (const float*)d_in[1];
  const float* Wq     = (const float*)d_in[2];
  const float* Wk     = (const float*)d_in[3];
  const float* Wv     = (const float*)d_in[4];
  const float* Wb     = (const float*)d_in[5];
  const float* Wo     = (const float*)d_in[6];
  const float* bo     = (const float*)d_in[7];
  const float* ln1_g  = (const float*)d_in[8];
  const float* ln1_b  = (const float*)d_in[9];
  const float* W_ffn1 = (const float*)d_in[10];
  const float* b_ffn1 = (const float*)d_in[11];
  const float* W_ffn2 = (const float*)d_in[12];
  const float* b_ffn2 = (const float*)d_in[13];
  const float* ln2_g  = (const float*)d_in[14];
  const float* ln2_b  = (const float*)d_in[15];
  const float* Wp1    = (const float*)d_in[16];
  const float* bp1    = (const float*)d_in[17];
  const float* Wp2    = (const float*)d_in[18];
  const float* bp2    = (const float*)d_in[19];
  const float* Wz     = (const float*)d_in[20];
  const float* bz     = (const float*)d_in[21];
  const float* lnp_g  = (const float*)d_in[22];
  const float* lnp_b  = (const float*)d_in[23];

  float* ws   = (float*)d_ws;
  float* qkv  = ws;                   // 640*384    = 245760
  float* bias = qkv + 245760;         // 2*8*320*320= 1638400
  float* ao   = bias + 1638400;       // 640*128    = 81920
  float* p1   = ao + 81920;           // 640*32     = 20480
  float* p2   = p1 + 20480;           // 640*32     = 20480
  float* T    = p2 + 20480;           // 640*2048   = 1310720  (total ~13.3 MB)

  float* out_x = (float*)d_out;           // 81920
  float* out_z = out_x + 81920;           // 13107200

  hipLaunchKernelGGL(k1_ln_qkv, dim3(NR / 2), dim3(256), 0, stream,
                     x, Wq, Wk, Wv, ln1_g, ln1_b, qkv);
  hipLaunchKernelGGL(k2_bias, dim3(L / 64, L, NB), dim3(256), 0, stream,
                     z, Wb, bias);
  hipLaunchKernelGGL(k3_attn, dim3(L / 8, H, NB), dim3(512), 0, stream,
                     qkv, bias, ao);
  hipLaunchKernelGGL(k45_rowpass, dim3(NR), dim3(512), 0, stream,
                     x, ao, Wo, bo, ln2_g, ln2_b, W_ffn1, b_ffn1,
                     W_ffn2, b_ffn2, Wp1, bp1, Wp2, bp2, Wz, out_x, p1, p2, T);
  hipLaunchKernelGGL(k6_zout, dim3(4, L, NB), dim3(256), 0, stream,
                     z, T, p2, bz, lnp_g, lnp_b, out_z);
}